// Round 6
// baseline (426.978 us; speedup 1.0000x reference)
//
#include <hip/hip_runtime.h>

#define K_CODES 1024
#define DIM     256
#define NROWS   65536      // 64*32*32
#define THREADS 128        // 2 waves per block, sharing 32 rows, splitting codes
#define ROWS_PER_BLOCK 32
#define NBLOCKS (NROWS / ROWS_PER_BLOCK)   // 2048
#define CHUNKS_PER_WAVE 32                 // 32 chunks x 16 codes = half codebook

typedef __attribute__((ext_vector_type(8))) short short8;
typedef __attribute__((ext_vector_type(4))) float f32x4;

__device__ __forceinline__ unsigned short f2bf(float f) {
    unsigned int u = __float_as_uint(f);
    u += 0x7fffu + ((u >> 16) & 1u);          // round-to-nearest-even
    return (unsigned short)(u >> 16);
}

// ---- kernel 0: pack codebook into MFMA-B-fragment order + hne table ----
// embb2 record (c,m) lane l (16B): e[c*16 + (l&15)][m*32 + (l>>4)*8 + j], j=0..7
__global__ void k_prep(const float* __restrict__ emb,
                       unsigned short* __restrict__ embb2,
                       float* __restrict__ hneT,
                       float* __restrict__ lossAcc) {
    __shared__ float snormw[8][16];
    const int c   = blockIdx.x;        // chunk of 16 codes
    const int tid = threadIdx.x;
    const int m   = tid >> 6;          // fragment 0..7 (one wave each)
    const int l   = tid & 63;
    const int r   = l & 15;
    const int q   = l >> 4;

    const float* src = emb + (size_t)(c * 16 + r) * DIM + m * 32 + q * 8;
    float4 a = *reinterpret_cast<const float4*>(src);
    float4 b = *reinterpret_cast<const float4*>(src + 4);
    float s = a.x*a.x + a.y*a.y + a.z*a.z + a.w*a.w
            + b.x*b.x + b.y*b.y + b.z*b.z + b.w*b.w;
    short8 sv;
    sv[0]=(short)f2bf(a.x); sv[1]=(short)f2bf(a.y); sv[2]=(short)f2bf(a.z); sv[3]=(short)f2bf(a.w);
    sv[4]=(short)f2bf(b.x); sv[5]=(short)f2bf(b.y); sv[6]=(short)f2bf(b.z); sv[7]=(short)f2bf(b.w);
    reinterpret_cast<short8*>(embb2)[(size_t)(c * 8 + m) * 64 + l] = sv;

    s += __shfl_xor(s, 16, 64);
    s += __shfl_xor(s, 32, 64);
    if (l < 16) snormw[m][l] = s;
    __syncthreads();
    if (tid < 16) {
        float t = 0.f;
        #pragma unroll
        for (int mm = 0; mm < 8; ++mm) t += snormw[mm][tid];
        hneT[c * 16 + tid] = -0.5f * t;
    }
    if (c == 0 && tid == 0) *lossAcc = 0.f;
}

// ---- kernel 1: code-split MFMA scan; 2 waves share 32 rows ----
__launch_bounds__(THREADS, 4)
__global__ void k_main(const float* __restrict__ z,
                       const unsigned short* __restrict__ embb2,
                       const float* __restrict__ hneT,
                       const float* __restrict__ emb,
                       float* __restrict__ out,
                       float* __restrict__ lossAcc) {
    __shared__ float skey[2][32];
    __shared__ float szn[32];

    const int tid  = threadIdx.x;
    const int lane = tid & 63;
    const int w    = tid >> 6;            // 0..1 : code half
    const int r    = lane & 15;
    const int q    = lane >> 4;           // 0..3
    const long grow0 = (long)blockIdx.x * ROWS_PER_BLOCK;

    // ---- A fragments (bf16, regs) + exact f32 row norms (same rows, both waves) ----
    short8 af[2][8];
    float  zn[2];
    #pragma unroll
    for (int t = 0; t < 2; ++t) {
        const float* zr = z + (grow0 + t * 16 + r) * DIM + q * 8;
        float s = 0.f;
        #pragma unroll
        for (int m = 0; m < 8; ++m) {
            float4 a = *reinterpret_cast<const float4*>(zr + m * 32);
            float4 b = *reinterpret_cast<const float4*>(zr + m * 32 + 4);
            s += a.x*a.x + a.y*a.y + a.z*a.z + a.w*a.w
               + b.x*b.x + b.y*b.y + b.z*b.z + b.w*b.w;
            short8 sv;
            sv[0]=(short)f2bf(a.x); sv[1]=(short)f2bf(a.y); sv[2]=(short)f2bf(a.z); sv[3]=(short)f2bf(a.w);
            sv[4]=(short)f2bf(b.x); sv[5]=(short)f2bf(b.y); sv[6]=(short)f2bf(b.z); sv[7]=(short)f2bf(b.w);
            af[t][m] = sv;
        }
        s += __shfl_xor(s, 16, 64);
        s += __shfl_xor(s, 32, 64);
        zn[t] = s;                        // norm of row (t*16 + r), all lanes
    }
    if (w == 0 && lane < 16) { szn[lane] = zn[0]; szn[16 + lane] = zn[1]; }

    float kb0[4], kb1[4];
    #pragma unroll
    for (int j = 0; j < 4; ++j) { kb0[j] = -1e30f; kb1[j] = -1e30f; }

    // wave w scans global chunks [w*32, w*32+32)
    const int c0 = w * CHUNKS_PER_WAVE;
    const char* ebase = reinterpret_cast<const char*>(embb2)
                        + (size_t)c0 * 8192 + (size_t)lane * 16;

    auto loadc = [&](short8 (&buf)[8], int c) {    // c relative to c0
        const char* bp = ebase + (size_t)c * 8192;
        #pragma unroll
        for (int m = 0; m < 8; ++m)
            buf[m] = *reinterpret_cast<const short8*>(bp + m * 1024);
    };
    auto compute = [&](short8 (&buf)[8], int c) {
        const int gcode = (c0 + c) * 16 + r;
        const float hne = hneT[gcode];
        f32x4 a0 = {hne, hne, hne, hne};
        f32x4 a1 = {hne, hne, hne, hne};
        #pragma unroll
        for (int m = 0; m < 8; ++m) {
            a0 = __builtin_amdgcn_mfma_f32_16x16x32_bf16(af[0][m], buf[m], a0, 0, 0, 0);
            a1 = __builtin_amdgcn_mfma_f32_16x16x32_bf16(af[1][m], buf[m], a1, 0, 0, 0);
        }
        const unsigned tag = 1023u - (unsigned)gcode;
        #pragma unroll
        for (int j = 0; j < 4; ++j) {
            kb0[j] = fmaxf(kb0[j], __uint_as_float((__float_as_uint(a0[j]) & 0xFFFFFC00u) | tag));
            kb1[j] = fmaxf(kb1[j], __uint_as_float((__float_as_uint(a1[j]) & 0xFFFFFC00u) | tag));
        }
    };

    // ---- software-pipelined scan: static double buffer, 2x unrolled ----
    short8 bufA[8], bufB[8];
    loadc(bufA, 0);
    for (int c = 0; c < CHUNKS_PER_WAVE; c += 2) {
        loadc(bufB, c + 1);
        compute(bufA, c);
        if (c + 2 < CHUNKS_PER_WAVE) loadc(bufA, c + 2);
        compute(bufB, c + 1);
    }

    // ---- cross-lane max over the 16 code-lanes ----
    #pragma unroll
    for (int j = 0; j < 4; ++j) {
        #pragma unroll
        for (int m = 1; m < 16; m <<= 1) {
            kb0[j] = fmaxf(kb0[j], __shfl_xor(kb0[j], m, 64));
            kb1[j] = fmaxf(kb1[j], __shfl_xor(kb1[j], m, 64));
        }
    }

    // ---- publish per-row keys; merge the two code-halves via fmax ----
    #pragma unroll
    for (int rr = 0; rr < 32; ++rr) {
        const int t = rr >> 4, r16 = rr & 15;
        const int qq = r16 >> 2, rsub = r16 & 3;
        const float kv = (t == 0) ? kb0[rsub] : kb1[rsub];
        if (lane == qq * 16) skey[w][rr] = kv;   // reduced value lives in group qq
    }
    __syncthreads();

    // ---- gather: wave w handles rows {2i + w}; 1 KB coalesced per instr ----
    #pragma unroll
    for (int i = 0; i < 16; ++i) {
        const int rr = i * 2 + w;
        const float kv = fmaxf(skey[0][rr], skey[1][rr]);
        const unsigned ku = __float_as_uint(kv);
        const int code = 1023 - (int)(ku & 1023u);
        float4 v = *reinterpret_cast<const float4*>(emb + (size_t)code * DIM + lane * 4);
        *reinterpret_cast<float4*>(out + (size_t)(grow0 + rr) * DIM + lane * 4) = v;
    }

    // ---- loss partial (wave 0): sum over rows of (||z||^2 - 2*score) ----
    if (w == 0) {
        float lp = 0.f;
        if (lane < 32) {
            const float kv = fmaxf(skey[0][lane], skey[1][lane]);
            const float score = __uint_as_float(__float_as_uint(kv) & 0xFFFFFC00u);
            lp = szn[lane] - 2.f * score;        // = ||z_row - e_code||^2
        }
        #pragma unroll
        for (int m = 1; m < 64; m <<= 1) lp += __shfl_xor(lp, m, 64);
        if (lane == 0) atomicAdd(lossAcc, lp);
    }
}

// ---- kernel 2: finalize losses ----
__global__ void k_loss(const float* __restrict__ lossAcc, float* __restrict__ out2) {
    float loss = 0.5f * lossAcc[0] * (1.f / 16777216.f);   // 0.5 * mean over N*D
    out2[0] = loss;
    out2[1] = loss;
}

extern "C" void kernel_launch(void* const* d_in, const int* in_sizes, int n_in,
                              void* d_out, int out_size, void* d_ws, size_t ws_size,
                              hipStream_t stream) {
    const float* z   = (const float*)d_in[0];
    const float* emb = (const float*)d_in[1];
    float* out = (float*)d_out;
    char*  ws  = (char*)d_ws;
    float* lossAcc        = (float*)ws;                         // 4 B
    float* hneT           = (float*)(ws + 256);                 // 4 KB: -||e||^2/2
    unsigned short* embb2 = (unsigned short*)(ws + 256 + 4096); // 512 KB packed

    k_prep<<<K_CODES / 16, 512, 0, stream>>>(emb, embb2, hneT, lossAcc);
    k_main<<<NBLOCKS, THREADS, 0, stream>>>(z, embb2, hneT, emb, out, lossAcc);
    k_loss<<<1, 1, 0, stream>>>(lossAcc, out + (long)NROWS * DIM);
}

// Round 7
// 163.385 us; speedup vs baseline: 2.6133x; 2.6133x over previous
//
#include <hip/hip_runtime.h>

#define K_CODES 1024
#define DIM     256
#define NROWS   65536      // 64*32*32
#define THREADS 256        // 4 waves per block
#define ROWS_PER_WAVE 32
#define ROWS_PER_BLOCK 128
#define NBLOCKS (NROWS / ROWS_PER_BLOCK)     // 512
#define CHUNK_CODES 32
#define NCHUNK (K_CODES / CHUNK_CODES)       // 32
#define CHUNK_BYTES (CHUNK_CODES * DIM * 2)  // 16384

typedef __attribute__((ext_vector_type(8))) short short8;
typedef __attribute__((ext_vector_type(4))) float f32x4;

__device__ __forceinline__ unsigned short f2bf(float f) {
    unsigned int u = __float_as_uint(f);
    u += 0x7fffu + ((u >> 16) & 1u);          // round-to-nearest-even
    return (unsigned short)(u >> 16);
}

// async global -> LDS, 16 bytes per lane (fire-and-forget, no dest VGPR)
__device__ __forceinline__ void gload_lds16(const void* g, void* l) {
    __builtin_amdgcn_global_load_lds(
        (const __attribute__((address_space(1))) void*)g,
        (__attribute__((address_space(3))) void*)l, 16, 0, 0);
}

// ---- kernel 0: pack codebook into MFMA-B-fragment order + hne table ----
// embb2 record (c16,m) lane l (16B): e[c16*16 + (l&15)][m*32 + (l>>4)*8 + j]
// -> 16-code chunk = 8 KB contiguous; k_main stages 32-code chunks (16 KB).
__global__ void k_prep(const float* __restrict__ emb,
                       unsigned short* __restrict__ embb2,
                       float* __restrict__ hneT,
                       float* __restrict__ lossAcc) {
    __shared__ float snormw[8][16];
    const int c   = blockIdx.x;        // chunk of 16 codes
    const int tid = threadIdx.x;
    const int m   = tid >> 6;          // fragment 0..7 (one wave each)
    const int l   = tid & 63;
    const int r   = l & 15;
    const int q   = l >> 4;

    const float* src = emb + (size_t)(c * 16 + r) * DIM + m * 32 + q * 8;
    float4 a = *reinterpret_cast<const float4*>(src);
    float4 b = *reinterpret_cast<const float4*>(src + 4);
    float s = a.x*a.x + a.y*a.y + a.z*a.z + a.w*a.w
            + b.x*b.x + b.y*b.y + b.z*b.z + b.w*b.w;
    short8 sv;
    sv[0]=(short)f2bf(a.x); sv[1]=(short)f2bf(a.y); sv[2]=(short)f2bf(a.z); sv[3]=(short)f2bf(a.w);
    sv[4]=(short)f2bf(b.x); sv[5]=(short)f2bf(b.y); sv[6]=(short)f2bf(b.z); sv[7]=(short)f2bf(b.w);
    reinterpret_cast<short8*>(embb2)[(size_t)(c * 8 + m) * 64 + l] = sv;

    s += __shfl_xor(s, 16, 64);
    s += __shfl_xor(s, 32, 64);
    if (l < 16) snormw[m][l] = s;
    __syncthreads();
    if (tid < 16) {
        float t = 0.f;
        #pragma unroll
        for (int mm = 0; mm < 8; ++mm) t += snormw[mm][tid];
        hneT[c * 16 + tid] = -0.5f * t;
    }
    if (c == 0 && tid == 0) *lossAcc = 0.f;
}

// ---- kernel 1: LDS-staged (global_load_lds) MFMA scan, 4 waves share B ----
__launch_bounds__(THREADS, 2)
__global__ void k_main(const float* __restrict__ z,
                       const unsigned short* __restrict__ embb2,
                       const float* __restrict__ hneT,
                       const float* __restrict__ emb,
                       float* __restrict__ out,
                       float* __restrict__ lossAcc) {
    __shared__ __align__(16) char ebuf[2][CHUNK_BYTES];   // 32 KB double buffer

    const int tid  = threadIdx.x;
    const int lane = tid & 63;
    const int w    = tid >> 6;            // 0..3
    const int r    = lane & 15;
    const int q    = lane >> 4;           // 0..3
    const long grow0 = (long)blockIdx.x * ROWS_PER_BLOCK + w * ROWS_PER_WAVE;

    // stage chunk 0 first (latency hides under the A-load/convert phase)
    {
        const char* src = reinterpret_cast<const char*>(embb2) + (size_t)tid * 16;
        char* dst = ebuf[0] + tid * 16;
        #pragma unroll
        for (int j = 0; j < 4; ++j)
            gload_lds16(src + j * 4096, dst + j * 4096);
    }

    // ---- A fragments (bf16, regs) + exact f32 row norms ----
    short8 af[2][8];
    float  zn[2];
    #pragma unroll
    for (int t = 0; t < 2; ++t) {
        const float* zr = z + (grow0 + t * 16 + r) * DIM + q * 8;
        float s = 0.f;
        #pragma unroll
        for (int m = 0; m < 8; ++m) {
            float4 a = *reinterpret_cast<const float4*>(zr + m * 32);
            float4 b = *reinterpret_cast<const float4*>(zr + m * 32 + 4);
            s += a.x*a.x + a.y*a.y + a.z*a.z + a.w*a.w
               + b.x*b.x + b.y*b.y + b.z*b.z + b.w*b.w;
            short8 sv;
            sv[0]=(short)f2bf(a.x); sv[1]=(short)f2bf(a.y); sv[2]=(short)f2bf(a.z); sv[3]=(short)f2bf(a.w);
            sv[4]=(short)f2bf(b.x); sv[5]=(short)f2bf(b.y); sv[6]=(short)f2bf(b.z); sv[7]=(short)f2bf(b.w);
            af[t][m] = sv;
        }
        s += __shfl_xor(s, 16, 64);
        s += __shfl_xor(s, 32, 64);
        zn[t] = s;                        // norm of row (t*16 + r), all lanes
    }

    float kb0[4], kb1[4];
    #pragma unroll
    for (int j = 0; j < 4; ++j) { kb0[j] = -1e30f; kb1[j] = -1e30f; }

    __syncthreads();   // chunk-0 stage complete (compiler drains vmcnt)

    for (int c = 0; c < NCHUNK; ++c) {
        const int cur = c & 1;
        // prefetch next chunk into the other buffer (fire-and-forget)
        if (c + 1 < NCHUNK) {
            const char* src = reinterpret_cast<const char*>(embb2)
                              + (size_t)(c + 1) * CHUNK_BYTES + (size_t)tid * 16;
            char* dst = ebuf[cur ^ 1] + tid * 16;
            #pragma unroll
            for (int j = 0; j < 4; ++j)
                gload_lds16(src + j * 4096, dst + j * 4096);
        }

        const float hne0 = hneT[c * CHUNK_CODES + r];
        const float hne1 = hneT[c * CHUNK_CODES + 16 + r];
        const char* bbase = ebuf[cur] + (size_t)lane * 16;

        #pragma unroll
        for (int g = 0; g < 2; ++g) {
            short8 bf[8];
            #pragma unroll
            for (int m = 0; m < 8; ++m)
                bf[m] = *reinterpret_cast<const short8*>(bbase + (g * 8 + m) * 1024);
            const float hne = (g == 0) ? hne0 : hne1;
            f32x4 a0 = {hne, hne, hne, hne};
            f32x4 a1 = {hne, hne, hne, hne};
            #pragma unroll
            for (int m = 0; m < 8; ++m) {
                a0 = __builtin_amdgcn_mfma_f32_16x16x32_bf16(af[0][m], bf[m], a0, 0, 0, 0);
                a1 = __builtin_amdgcn_mfma_f32_16x16x32_bf16(af[1][m], bf[m], a1, 0, 0, 0);
            }
            // tagged running argmax of (z.e - ||e||^2/2); low 10 bits = 1023-code
            const unsigned tag = 1023u - (unsigned)(c * CHUNK_CODES + g * 16 + r);
            #pragma unroll
            for (int j = 0; j < 4; ++j) {
                kb0[j] = fmaxf(kb0[j], __uint_as_float((__float_as_uint(a0[j]) & 0xFFFFFC00u) | tag));
                kb1[j] = fmaxf(kb1[j], __uint_as_float((__float_as_uint(a1[j]) & 0xFFFFFC00u) | tag));
            }
        }
        __syncthreads();   // prefetch landed + all waves done reading ebuf[cur]
    }

    // ---- cross-lane max over the 16 code-lanes ----
    #pragma unroll
    for (int j = 0; j < 4; ++j) {
        #pragma unroll
        for (int m = 1; m < 16; m <<= 1) {
            kb0[j] = fmaxf(kb0[j], __shfl_xor(kb0[j], m, 64));
            kb1[j] = fmaxf(kb1[j], __shfl_xor(kb1[j], m, 64));
        }
    }

    // ---- epilogue: per-row gather (1 KB coalesced per instr) + loss ----
    float lp = 0.f;
    #pragma unroll
    for (int rr = 0; rr < 32; ++rr) {
        const int t = rr >> 4, r16 = rr & 15;
        const int qq = r16 >> 2, rsub = r16 & 3;
        float kv = __shfl((t == 0) ? kb0[rsub] : kb1[rsub], qq * 16, 64);
        const unsigned ku = __float_as_uint(kv);
        const int   code  = 1023 - (int)(ku & 1023u);
        const float score = __uint_as_float(ku & 0xFFFFFC00u);   // dot - ||e||^2/2
        float4 v = *reinterpret_cast<const float4*>(emb + (size_t)code * DIM + lane * 4);
        *reinterpret_cast<float4*>(out + (size_t)(grow0 + rr) * DIM + lane * 4) = v;
        float zr = __shfl(zn[t], r16, 64);                        // ||z_row||^2
        lp += zr - 2.f * score;                                   // = ||z - e||^2
    }
    if (lane == 0) atomicAdd(lossAcc, lp);   // lp identical across lanes
}

// ---- kernel 2: finalize losses ----
__global__ void k_loss(const float* __restrict__ lossAcc, float* __restrict__ out2) {
    float loss = 0.5f * lossAcc[0] * (1.f / 16777216.f);   // 0.5 * mean over N*D
    out2[0] = loss;
    out2[1] = loss;
}

extern "C" void kernel_launch(void* const* d_in, const int* in_sizes, int n_in,
                              void* d_out, int out_size, void* d_ws, size_t ws_size,
                              hipStream_t stream) {
    const float* z   = (const float*)d_in[0];
    const float* emb = (const float*)d_in[1];
    float* out = (float*)d_out;
    char*  ws  = (char*)d_ws;
    float* lossAcc        = (float*)ws;                         // 4 B
    float* hneT           = (float*)(ws + 256);                 // 4 KB: -||e||^2/2
    unsigned short* embb2 = (unsigned short*)(ws + 256 + 4096); // 512 KB packed

    k_prep<<<K_CODES / 16, 512, 0, stream>>>(emb, embb2, hneT, lossAcc);
    k_main<<<NBLOCKS, THREADS, 0, stream>>>(z, embb2, hneT, emb, out, lossAcc);
    k_loss<<<1, 1, 0, stream>>>(lossAcc, out + (long)NROWS * DIM);
}

// Round 8
// 155.034 us; speedup vs baseline: 2.7541x; 1.0539x over previous
//
#include <hip/hip_runtime.h>

#define K_CODES 1024
#define DIM     256
#define NROWS   65536      // 64*32*32
#define THREADS 256        // 4 waves per block
#define ROWS_PER_WAVE 16
#define ROWS_PER_BLOCK 64
#define NBLOCKS (NROWS / ROWS_PER_BLOCK)     // 1024
#define CHUNK_CODES 32
#define NCHUNK (K_CODES / CHUNK_CODES)       // 32
#define CHUNK_BYTES (CHUNK_CODES * DIM * 2)  // 16384

typedef __attribute__((ext_vector_type(8))) short short8;
typedef __attribute__((ext_vector_type(4))) float f32x4;

__device__ __forceinline__ unsigned short f2bf(float f) {
    unsigned int u = __float_as_uint(f);
    u += 0x7fffu + ((u >> 16) & 1u);          // round-to-nearest-even
    return (unsigned short)(u >> 16);
}

// async global -> LDS, 16 bytes per lane (fire-and-forget, no dest VGPR)
__device__ __forceinline__ void gload_lds16(const void* g, void* l) {
    __builtin_amdgcn_global_load_lds(
        (const __attribute__((address_space(1))) void*)g,
        (__attribute__((address_space(3))) void*)l, 16, 0, 0);
}

// ---- kernel 0: pack codebook into MFMA-B-fragment order + hne table ----
// embb2 record (c16,m) lane l (16B): e[c16*16 + (l&15)][m*32 + (l>>4)*8 + j]
__global__ void k_prep(const float* __restrict__ emb,
                       unsigned short* __restrict__ embb2,
                       float* __restrict__ hneT,
                       float* __restrict__ lossAcc) {
    __shared__ float snormw[8][16];
    const int c   = blockIdx.x;        // chunk of 16 codes
    const int tid = threadIdx.x;
    const int m   = tid >> 6;          // fragment 0..7 (one wave each)
    const int l   = tid & 63;
    const int r   = l & 15;
    const int q   = l >> 4;

    const float* src = emb + (size_t)(c * 16 + r) * DIM + m * 32 + q * 8;
    float4 a = *reinterpret_cast<const float4*>(src);
    float4 b = *reinterpret_cast<const float4*>(src + 4);
    float s = a.x*a.x + a.y*a.y + a.z*a.z + a.w*a.w
            + b.x*b.x + b.y*b.y + b.z*b.z + b.w*b.w;
    short8 sv;
    sv[0]=(short)f2bf(a.x); sv[1]=(short)f2bf(a.y); sv[2]=(short)f2bf(a.z); sv[3]=(short)f2bf(a.w);
    sv[4]=(short)f2bf(b.x); sv[5]=(short)f2bf(b.y); sv[6]=(short)f2bf(b.z); sv[7]=(short)f2bf(b.w);
    reinterpret_cast<short8*>(embb2)[(size_t)(c * 8 + m) * 64 + l] = sv;

    s += __shfl_xor(s, 16, 64);
    s += __shfl_xor(s, 32, 64);
    if (l < 16) snormw[m][l] = s;
    __syncthreads();
    if (tid < 16) {
        float t = 0.f;
        #pragma unroll
        for (int mm = 0; mm < 8; ++mm) t += snormw[mm][tid];
        hneT[c * 16 + tid] = -0.5f * t;
    }
    if (c == 0 && tid == 0) *lossAcc = 0.f;
}

// ---- kernel 1: 16 rows/wave, LDS-staged B, split-K MFMA, 16 waves/CU ----
__launch_bounds__(THREADS, 4)     // cap 128 VGPR -> 4 blocks/CU (16 waves)
__global__ void k_main(const float* __restrict__ z,
                       const unsigned short* __restrict__ embb2,
                       const float* __restrict__ hneT,
                       const float* __restrict__ emb,
                       float* __restrict__ out,
                       float* __restrict__ lossAcc) {
    __shared__ __align__(16) char ebuf[2][CHUNK_BYTES];   // 32 KB double buffer
    __shared__ float shne[K_CODES];                       // 4 KB
    __shared__ float swsum[4];

    const int tid  = threadIdx.x;
    const int lane = tid & 63;
    const int w    = tid >> 6;            // 0..3
    const int r    = lane & 15;
    const int q    = lane >> 4;           // 0..3
    const long grow0 = (long)blockIdx.x * ROWS_PER_BLOCK + w * ROWS_PER_WAVE;

    // stage chunk 0 (async, no dest VGPR) — latency hides under A-phase
    {
        const char* src = reinterpret_cast<const char*>(embb2) + (size_t)tid * 16;
        char* dst = ebuf[0] + tid * 16;
        #pragma unroll
        for (int j = 0; j < 4; ++j)
            gload_lds16(src + j * 4096, dst + j * 4096);
    }
    // stage -||e||^2/2 table to LDS
    #pragma unroll
    for (int i = 0; i < K_CODES / THREADS; ++i)
        shne[i * THREADS + tid] = hneT[i * THREADS + tid];

    // ---- A fragments (bf16, regs) + exact f32 row norm ----
    // 16x16x32 A layout: lane (q,r) holds A[row=r][k = m*32 + q*8 + j]
    short8 af[8];
    float  zn;
    {
        const float* zr = z + (grow0 + r) * DIM + q * 8;
        float s = 0.f;
        #pragma unroll
        for (int m = 0; m < 8; ++m) {
            float4 a = *reinterpret_cast<const float4*>(zr + m * 32);
            float4 b = *reinterpret_cast<const float4*>(zr + m * 32 + 4);
            s += a.x*a.x + a.y*a.y + a.z*a.z + a.w*a.w
               + b.x*b.x + b.y*b.y + b.z*b.z + b.w*b.w;
            short8 sv;
            sv[0]=(short)f2bf(a.x); sv[1]=(short)f2bf(a.y); sv[2]=(short)f2bf(a.z); sv[3]=(short)f2bf(a.w);
            sv[4]=(short)f2bf(b.x); sv[5]=(short)f2bf(b.y); sv[6]=(short)f2bf(b.z); sv[7]=(short)f2bf(b.w);
            af[m] = sv;
        }
        s += __shfl_xor(s, 16, 64);
        s += __shfl_xor(s, 32, 64);
        zn = s;                           // norm of row r (all lanes)
    }

    float kb[4];
    #pragma unroll
    for (int j = 0; j < 4; ++j) kb[j] = -1e30f;

    __syncthreads();   // chunk-0 stage + shne complete

    for (int c = 0; c < NCHUNK; ++c) {
        const int cur = c & 1;
        if (c + 1 < NCHUNK) {             // prefetch next chunk (fire-and-forget)
            const char* src = reinterpret_cast<const char*>(embb2)
                              + (size_t)(c + 1) * CHUNK_BYTES + (size_t)tid * 16;
            char* dst = ebuf[cur ^ 1] + tid * 16;
            #pragma unroll
            for (int j = 0; j < 4; ++j)
                gload_lds16(src + j * 4096, dst + j * 4096);
        }

        // hne loads issued early (LDS), consumed only after the MFMA chains
        const float hne0 = shne[c * CHUNK_CODES + r];
        const float hne1 = shne[c * CHUNK_CODES + 16 + r];
        const char* bbase = ebuf[cur] + (size_t)lane * 16;

        #pragma unroll
        for (int g = 0; g < 2; ++g) {
            short8 bf[8];
            #pragma unroll
            for (int m = 0; m < 8; ++m)
                bf[m] = *reinterpret_cast<const short8*>(bbase + (g * 8 + m) * 1024);
            // split-K: two independent 4-deep chains
            f32x4 alo = {0.f, 0.f, 0.f, 0.f};
            f32x4 ahi = {0.f, 0.f, 0.f, 0.f};
            #pragma unroll
            for (int m = 0; m < 4; ++m) {
                alo = __builtin_amdgcn_mfma_f32_16x16x32_bf16(af[m],     bf[m],     alo, 0, 0, 0);
                ahi = __builtin_amdgcn_mfma_f32_16x16x32_bf16(af[m + 4], bf[m + 4], ahi, 0, 0, 0);
            }
            const float hne = (g == 0) ? hne0 : hne1;
            const unsigned tag = 1023u - (unsigned)(c * CHUNK_CODES + g * 16 + r);
            #pragma unroll
            for (int j = 0; j < 4; ++j) {
                float sc = alo[j] + ahi[j] + hne;            // dot - ||e||^2/2
                kb[j] = fmaxf(kb[j], __uint_as_float((__float_as_uint(sc) & 0xFFFFFC00u) | tag));
            }
        }
        __syncthreads();   // prefetch landed + all waves done with ebuf[cur]
    }

    // ---- cross-lane max over the 16 code-lanes ----
    #pragma unroll
    for (int j = 0; j < 4; ++j) {
        #pragma unroll
        for (int m = 1; m < 16; m <<= 1)
            kb[j] = fmaxf(kb[j], __shfl_xor(kb[j], m, 64));
    }

    // ---- epilogue: per-row gather (1 KB coalesced per instr) + loss ----
    float lp = 0.f;
    #pragma unroll
    for (int rr = 0; rr < 16; ++rr) {
        const int qq = rr >> 2, j = rr & 3;
        float kv = __shfl(kb[j], qq * 16, 64);
        const unsigned ku = __float_as_uint(kv);
        const int   code  = 1023 - (int)(ku & 1023u);
        const float score = __uint_as_float(ku & 0xFFFFFC00u);   // dot - ||e||^2/2
        float4 v = *reinterpret_cast<const float4*>(emb + (size_t)code * DIM + lane * 4);
        *reinterpret_cast<float4*>(out + (size_t)(grow0 + rr) * DIM + lane * 4) = v;
        float zr = __shfl(zn, rr, 64);                            // ||z_row||^2
        lp += zr - 2.f * score;                                   // = ||z - e||^2
    }
    // block-level loss reduction: 1 atomic per block
    if (lane == 0) swsum[w] = lp;
    __syncthreads();
    if (tid == 0)
        atomicAdd(lossAcc, swsum[0] + swsum[1] + swsum[2] + swsum[3]);
}

// ---- kernel 2: finalize losses ----
__global__ void k_loss(const float* __restrict__ lossAcc, float* __restrict__ out2) {
    float loss = 0.5f * lossAcc[0] * (1.f / 16777216.f);   // 0.5 * mean over N*D
    out2[0] = loss;
    out2[1] = loss;
}

extern "C" void kernel_launch(void* const* d_in, const int* in_sizes, int n_in,
                              void* d_out, int out_size, void* d_ws, size_t ws_size,
                              hipStream_t stream) {
    const float* z   = (const float*)d_in[0];
    const float* emb = (const float*)d_in[1];
    float* out = (float*)d_out;
    char*  ws  = (char*)d_ws;
    float* lossAcc        = (float*)ws;                         // 4 B
    float* hneT           = (float*)(ws + 256);                 // 4 KB: -||e||^2/2
    unsigned short* embb2 = (unsigned short*)(ws + 256 + 4096); // 512 KB packed

    k_prep<<<K_CODES / 16, 512, 0, stream>>>(emb, embb2, hneT, lossAcc);
    k_main<<<NBLOCKS, THREADS, 0, stream>>>(z, embb2, hneT, emb, out, lossAcc);
    k_loss<<<1, 1, 0, stream>>>(lossAcc, out + (long)NROWS * DIM);
}